// Round 2
// baseline (5780.848 us; speedup 1.0000x reference)
//
#include <hip/hip_runtime.h>
#include <math.h>

#define NN 50000
#define NE 1600000
#define CH 128
#define LAT 32

// ---------------- degree count: cnt[dst] += 1 ----------------
__global__ void k_count(const int* __restrict__ dst, float* __restrict__ cnt) {
  int e = blockIdx.x * 256 + threadIdx.x;
  if (e < NE) atomicAdd(&cnt[dst[e]], 1.0f);
}

// ---------------- scatter-add: agg[dst] += feat[src], 128 ch ----------------
// 32 lanes per edge, float4 per lane -> coalesced 512B row read per edge.
__global__ void k_scatter(const int* __restrict__ src, const int* __restrict__ dst,
                          const float* __restrict__ feat, float* __restrict__ agg) {
  int t = blockIdx.x * 256 + threadIdx.x;
  int e = t >> 5, q = t & 31;
  if (e >= NE) return;
  int s = src[e], d = dst[e];
  const float4 v = *reinterpret_cast<const float4*>(feat + s * CH + q * 4);
  float* p = agg + d * CH + q * 4;
  atomicAdd(p + 0, v.x);
  atomicAdd(p + 1, v.y);
  atomicAdd(p + 2, v.z);
  atomicAdd(p + 3, v.w);
}

// ---------------- fused SAGE layer ----------------
// out[v] = relu( (agg[v]/max(cnt[v],1)) @ Wl + h[v] @ Wr + b )
// 32 nodes per block, 256 threads, 4x4 register tile per thread.
// `out` may alias `agg` (block reads its rows into LDS before writing).
__global__ __launch_bounds__(256) void k_sage(
    const float* __restrict__ agg, const float* __restrict__ h,
    const float* __restrict__ cnt,
    const float* __restrict__ Wl, const float* __restrict__ Wr,
    const float* __restrict__ bias, float* __restrict__ out) {
  __shared__ float mean_s[32][128];
  __shared__ float h_s[32][128];
  __shared__ float rcp_s[32];
  int tid = threadIdx.x;
  int nbase = blockIdx.x * 32;

  if (tid < 32) {
    int v = nbase + tid;
    float c = (v < NN) ? cnt[v] : 1.0f;
    rcp_s[tid] = 1.0f / fmaxf(c, 1.0f);
  }
  __syncthreads();

  // stage agg (scaled to mean) and h into LDS
  for (int f = tid; f < 1024; f += 256) {
    int row = f >> 5;
    int c4 = (f & 31) * 4;
    int v = nbase + row;
    float4 a = make_float4(0.f, 0.f, 0.f, 0.f);
    float4 hh = make_float4(0.f, 0.f, 0.f, 0.f);
    if (v < NN) {
      a = *reinterpret_cast<const float4*>(agg + v * CH + c4);
      hh = *reinterpret_cast<const float4*>(h + v * CH + c4);
    }
    float r = rcp_s[row];
    *reinterpret_cast<float4*>(&mean_s[row][c4]) =
        make_float4(a.x * r, a.y * r, a.z * r, a.w * r);
    *reinterpret_cast<float4*>(&h_s[row][c4]) = hh;
  }
  __syncthreads();

  int jg = tid & 31, ng = tid >> 5;
  int j0 = jg * 4, nl = ng * 4;
  float acc[4][4];
#pragma unroll
  for (int a = 0; a < 4; a++)
#pragma unroll
    for (int b = 0; b < 4; b++) acc[a][b] = 0.f;

#pragma unroll 4
  for (int k = 0; k < 128; ++k) {
    float4 wl = *reinterpret_cast<const float4*>(Wl + k * CH + j0);
    float4 wr = *reinterpret_cast<const float4*>(Wr + k * CH + j0);
#pragma unroll
    for (int n = 0; n < 4; ++n) {
      float m = mean_s[nl + n][k];
      float hv = h_s[nl + n][k];
      acc[n][0] += m * wl.x + hv * wr.x;
      acc[n][1] += m * wl.y + hv * wr.y;
      acc[n][2] += m * wl.z + hv * wr.z;
      acc[n][3] += m * wl.w + hv * wr.w;
    }
  }

  float4 bb = *reinterpret_cast<const float4*>(bias + j0);
#pragma unroll
  for (int n = 0; n < 4; ++n) {
    int v = nbase + nl + n;
    if (v < NN) {
      float4 o;
      o.x = fmaxf(acc[n][0] + bb.x, 0.f);
      o.y = fmaxf(acc[n][1] + bb.y, 0.f);
      o.z = fmaxf(acc[n][2] + bb.z, 0.f);
      o.w = fmaxf(acc[n][3] + bb.w, 0.f);
      *reinterpret_cast<float4*>(out + v * CH + j0) = o;
    }
  }
}

// ---------------- mu / logvar heads + reparameterize ----------------
__global__ __launch_bounds__(256) void k_heads(
    const float* __restrict__ h2, const float* __restrict__ eps,
    const float* __restrict__ Wmu, const float* __restrict__ bmu,
    const float* __restrict__ Wlv, const float* __restrict__ blv,
    float* __restrict__ mu_out, float* __restrict__ lv_out,
    float* __restrict__ z) {
  __shared__ float hs[32][132];  // +4 pad: kills 8-way bank conflict on hs[n][k]
  int tid = threadIdx.x;
  int nbase = blockIdx.x * 32;

  for (int f = tid; f < 1024; f += 256) {
    int row = f >> 5;
    int c4 = (f & 31) * 4;
    int v = nbase + row;
    float4 hh = make_float4(0.f, 0.f, 0.f, 0.f);
    if (v < NN) hh = *reinterpret_cast<const float4*>(h2 + v * CH + c4);
    *reinterpret_cast<float4*>(&hs[row][c4]) = hh;
  }
  __syncthreads();

  int n = tid >> 3;
  int j0 = (tid & 7) * 4;
  float am[4] = {0.f, 0.f, 0.f, 0.f};
  float al[4] = {0.f, 0.f, 0.f, 0.f};
#pragma unroll 4
  for (int k = 0; k < 128; ++k) {
    float4 wm = *reinterpret_cast<const float4*>(Wmu + k * LAT + j0);
    float4 wv = *reinterpret_cast<const float4*>(Wlv + k * LAT + j0);
    float hv = hs[n][k];
    am[0] += hv * wm.x; am[1] += hv * wm.y; am[2] += hv * wm.z; am[3] += hv * wm.w;
    al[0] += hv * wv.x; al[1] += hv * wv.y; al[2] += hv * wv.z; al[3] += hv * wv.w;
  }
  int v = nbase + n;
  if (v < NN) {
    float4 bm = *reinterpret_cast<const float4*>(bmu + j0);
    float4 bl = *reinterpret_cast<const float4*>(blv + j0);
    float4 e4 = *reinterpret_cast<const float4*>(eps + v * LAT + j0);
    float4 mu, lv, zz;
    mu.x = am[0] + bm.x; mu.y = am[1] + bm.y; mu.z = am[2] + bm.z; mu.w = am[3] + bm.w;
    lv.x = al[0] + bl.x; lv.y = al[1] + bl.y; lv.z = al[2] + bl.z; lv.w = al[3] + bl.w;
    zz.x = mu.x + e4.x * expf(0.5f * lv.x);
    zz.y = mu.y + e4.y * expf(0.5f * lv.y);
    zz.z = mu.z + e4.z * expf(0.5f * lv.z);
    zz.w = mu.w + e4.w * expf(0.5f * lv.w);
    *reinterpret_cast<float4*>(mu_out + v * LAT + j0) = mu;
    *reinterpret_cast<float4*>(lv_out + v * LAT + j0) = lv;
    *reinterpret_cast<float4*>(z + v * LAT + j0) = zz;
  }
}

// ---------------- edge decode: sigmoid(z[src] . z[dst]) ----------------
// 8 lanes per edge, float4 per lane, shfl_xor reduce within the 8-lane group.
__global__ void k_decode(const int* __restrict__ src, const int* __restrict__ dst,
                         const float* __restrict__ z, float* __restrict__ probs) {
  int t = blockIdx.x * 256 + threadIdx.x;
  int e = t >> 3, part = t & 7;
  if (e >= NE) return;
  int s = src[e], d = dst[e];
  float4 a = *reinterpret_cast<const float4*>(z + s * LAT + part * 4);
  float4 b = *reinterpret_cast<const float4*>(z + d * LAT + part * 4);
  float p = a.x * b.x + a.y * b.y + a.z * b.z + a.w * b.w;
  p += __shfl_xor(p, 1);
  p += __shfl_xor(p, 2);
  p += __shfl_xor(p, 4);
  if (part == 0) probs[e] = 1.0f / (1.0f + expf(-p));
}

extern "C" void kernel_launch(void* const* d_in, const int* in_sizes, int n_in,
                              void* d_out, int out_size, void* d_ws, size_t ws_size,
                              hipStream_t stream) {
  const float* x   = (const float*)d_in[0];
  const int*   ei  = (const int*)d_in[1];
  const float* eps = (const float*)d_in[2];
  const float* Wl0 = (const float*)d_in[3];
  const float* Wr0 = (const float*)d_in[4];
  const float* b0  = (const float*)d_in[5];
  const float* Wl1 = (const float*)d_in[6];
  const float* Wr1 = (const float*)d_in[7];
  const float* b1  = (const float*)d_in[8];
  const float* Wmu = (const float*)d_in[9];
  const float* bmu = (const float*)d_in[10];
  const float* Wlv = (const float*)d_in[11];
  const float* blv = (const float*)d_in[12];
  const int* src = ei;
  const int* dst = ei + NE;

  float* ws  = (float*)d_ws;
  float* cnt = ws;                         // NN floats
  float* agg = ws + 50048;                 // NN*CH floats (also holds h2 later)
  float* h1  = agg + NN * CH;              // NN*CH floats
  float* z   = h1 + NN * CH;               // NN*LAT floats
  // total ~14.45M floats = ~57.8 MB of d_ws

  float* probs  = (float*)d_out;           // NE
  float* mu_out = probs + NE;              // NN*LAT
  float* lv_out = mu_out + NN * LAT;       // NN*LAT

  hipMemsetAsync(cnt, 0, NN * sizeof(float), stream);
  hipMemsetAsync(agg, 0, (size_t)NN * CH * sizeof(float), stream);

  k_count<<<(NE + 255) / 256, 256, 0, stream>>>(dst, cnt);
  k_scatter<<<(NE * 32 + 255) / 256, 256, 0, stream>>>(src, dst, x, agg);
  k_sage<<<(NN + 31) / 32, 256, 0, stream>>>(agg, x, cnt, Wl0, Wr0, b0, h1);

  hipMemsetAsync(agg, 0, (size_t)NN * CH * sizeof(float), stream);
  k_scatter<<<(NE * 32 + 255) / 256, 256, 0, stream>>>(src, dst, h1, agg);
  k_sage<<<(NN + 31) / 32, 256, 0, stream>>>(agg, h1, cnt, Wl1, Wr1, b1, agg);

  k_heads<<<(NN + 31) / 32, 256, 0, stream>>>(agg, eps, Wmu, bmu, Wlv, blv,
                                              mu_out, lv_out, z);
  k_decode<<<(NE * 8 + 255) / 256, 256, 0, stream>>>(src, dst, z, probs);
}

// Round 3
// 733.419 us; speedup vs baseline: 7.8821x; 7.8821x over previous
//
#include <hip/hip_runtime.h>
#include <math.h>

#define NN 50000
#define NE 1600000
#define CH 128
#define LAT 32
#define NB 196  // ceil(NN/256)

// ---------------- CSR build ----------------
__global__ void k_hist(const int* __restrict__ dst, int* __restrict__ deg) {
  int e = blockIdx.x * 256 + threadIdx.x;
  if (e < NE) atomicAdd(&deg[dst[e]], 1);
}

__global__ void k_scan1(const int* __restrict__ deg, int* __restrict__ bsum) {
  __shared__ int red[256];
  int i = blockIdx.x * 256 + threadIdx.x;
  red[threadIdx.x] = (i < NN) ? deg[i] : 0;
  __syncthreads();
  for (int s = 128; s > 0; s >>= 1) {
    if (threadIdx.x < s) red[threadIdx.x] += red[threadIdx.x + s];
    __syncthreads();
  }
  if (threadIdx.x == 0) bsum[blockIdx.x] = red[0];
}

__global__ void k_scan2(const int* __restrict__ bsum, int* __restrict__ boff) {
  __shared__ int tmp[256];
  int t = threadIdx.x;
  int v = (t < NB) ? bsum[t] : 0;
  tmp[t] = v;
  __syncthreads();
  for (int off = 1; off < 256; off <<= 1) {
    int add = (t >= off) ? tmp[t - off] : 0;
    __syncthreads();
    tmp[t] += add;
    __syncthreads();
  }
  if (t < NB) boff[t] = tmp[t] - v;  // exclusive
}

__global__ void k_scan3(const int* __restrict__ deg, const int* __restrict__ boff,
                        int* __restrict__ row_start, int* __restrict__ cursor) {
  __shared__ int tmp[256];
  int t = threadIdx.x;
  int i = blockIdx.x * 256 + t;
  int v = (i < NN) ? deg[i] : 0;
  tmp[t] = v;
  __syncthreads();
  for (int off = 1; off < 256; off <<= 1) {
    int add = (t >= off) ? tmp[t - off] : 0;
    __syncthreads();
    tmp[t] += add;
    __syncthreads();
  }
  int excl = tmp[t] - v + boff[blockIdx.x];
  if (i < NN) { row_start[i] = excl; cursor[i] = excl; }
}

__global__ void k_fill(const int* __restrict__ src, const int* __restrict__ dst,
                       int* __restrict__ cursor, int* __restrict__ eid) {
  int e = blockIdx.x * 256 + threadIdx.x;
  if (e < NE) {
    int d = dst[e];
    int pos = atomicAdd(&cursor[d], 1);
    eid[pos] = src[e];
  }
}

// ---------------- fused SAGE layer: pull-aggregate + GEMM + ReLU ----------------
// out[v] = relu( mean_{s in N(v)} feat[s] @ Wl + feat[v] @ Wr + b )
// 32 nodes/block, 256 threads. Phase 1: 8 half-waves gather-sum 4 nodes each
// (32 lanes x float4 = coalesced 512B row read per edge). Phase 2: 4x4 tile GEMM.
__global__ __launch_bounds__(256) void k_sage2(
    const float* __restrict__ feat, const int* __restrict__ deg,
    const int* __restrict__ row_start, const int* __restrict__ eid,
    const float* __restrict__ Wl, const float* __restrict__ Wr,
    const float* __restrict__ bias, float* __restrict__ out) {
  __shared__ float mean_s[32][128];
  __shared__ float h_s[32][128];
  int tid = threadIdx.x;
  int nbase = blockIdx.x * 32;
  int hw = tid >> 5, q = tid & 31;

  // Phase 1: pull aggregation
  for (int n = hw; n < 32; n += 8) {
    int v = nbase + n;
    float ax = 0.f, ay = 0.f, az = 0.f, aw = 0.f;
    float4 hh = make_float4(0.f, 0.f, 0.f, 0.f);
    if (v < NN) {
      int r0 = row_start[v];
      int dg = deg[v];
      int i = 0;
      for (; i + 3 < dg; i += 4) {
        int s0 = eid[r0 + i + 0];
        int s1 = eid[r0 + i + 1];
        int s2 = eid[r0 + i + 2];
        int s3 = eid[r0 + i + 3];
        float4 a = *reinterpret_cast<const float4*>(feat + (size_t)s0 * CH + q * 4);
        float4 b = *reinterpret_cast<const float4*>(feat + (size_t)s1 * CH + q * 4);
        float4 c = *reinterpret_cast<const float4*>(feat + (size_t)s2 * CH + q * 4);
        float4 d = *reinterpret_cast<const float4*>(feat + (size_t)s3 * CH + q * 4);
        ax += a.x + b.x + c.x + d.x;
        ay += a.y + b.y + c.y + d.y;
        az += a.z + b.z + c.z + d.z;
        aw += a.w + b.w + c.w + d.w;
      }
      for (; i < dg; ++i) {
        int s0 = eid[r0 + i];
        float4 a = *reinterpret_cast<const float4*>(feat + (size_t)s0 * CH + q * 4);
        ax += a.x; ay += a.y; az += a.z; aw += a.w;
      }
      float r = 1.0f / (float)max(dg, 1);
      ax *= r; ay *= r; az *= r; aw *= r;
      hh = *reinterpret_cast<const float4*>(feat + (size_t)v * CH + q * 4);
    }
    *reinterpret_cast<float4*>(&mean_s[n][q * 4]) = make_float4(ax, ay, az, aw);
    *reinterpret_cast<float4*>(&h_s[n][q * 4]) = hh;
  }
  __syncthreads();

  // Phase 2: GEMM  out[32 nodes][128] = mean @ Wl + h @ Wr + b, ReLU
  int jg = tid & 31, ng = tid >> 5;
  int j0 = jg * 4, nl = ng * 4;
  float acc[4][4];
#pragma unroll
  for (int a = 0; a < 4; a++)
#pragma unroll
    for (int b = 0; b < 4; b++) acc[a][b] = 0.f;

#pragma unroll 4
  for (int k = 0; k < 128; ++k) {
    float4 wl = *reinterpret_cast<const float4*>(Wl + k * CH + j0);
    float4 wr = *reinterpret_cast<const float4*>(Wr + k * CH + j0);
#pragma unroll
    for (int n = 0; n < 4; ++n) {
      float m = mean_s[nl + n][k];
      float hv = h_s[nl + n][k];
      acc[n][0] += m * wl.x + hv * wr.x;
      acc[n][1] += m * wl.y + hv * wr.y;
      acc[n][2] += m * wl.z + hv * wr.z;
      acc[n][3] += m * wl.w + hv * wr.w;
    }
  }

  float4 bb = *reinterpret_cast<const float4*>(bias + j0);
#pragma unroll
  for (int n = 0; n < 4; ++n) {
    int v = nbase + nl + n;
    if (v < NN) {
      float4 o;
      o.x = fmaxf(acc[n][0] + bb.x, 0.f);
      o.y = fmaxf(acc[n][1] + bb.y, 0.f);
      o.z = fmaxf(acc[n][2] + bb.z, 0.f);
      o.w = fmaxf(acc[n][3] + bb.w, 0.f);
      *reinterpret_cast<float4*>(out + (size_t)v * CH + j0) = o;
    }
  }
}

// ---------------- mu / logvar heads + reparameterize ----------------
__global__ __launch_bounds__(256) void k_heads(
    const float* __restrict__ h2, const float* __restrict__ eps,
    const float* __restrict__ Wmu, const float* __restrict__ bmu,
    const float* __restrict__ Wlv, const float* __restrict__ blv,
    float* __restrict__ mu_out, float* __restrict__ lv_out,
    float* __restrict__ z) {
  __shared__ float hs[32][132];  // +4 pad kills bank conflict on hs[n][k]
  int tid = threadIdx.x;
  int nbase = blockIdx.x * 32;

  for (int f = tid; f < 1024; f += 256) {
    int row = f >> 5;
    int c4 = (f & 31) * 4;
    int v = nbase + row;
    float4 hh = make_float4(0.f, 0.f, 0.f, 0.f);
    if (v < NN) hh = *reinterpret_cast<const float4*>(h2 + (size_t)v * CH + c4);
    *reinterpret_cast<float4*>(&hs[row][c4]) = hh;
  }
  __syncthreads();

  int n = tid >> 3;
  int j0 = (tid & 7) * 4;
  float am[4] = {0.f, 0.f, 0.f, 0.f};
  float al[4] = {0.f, 0.f, 0.f, 0.f};
#pragma unroll 4
  for (int k = 0; k < 128; ++k) {
    float4 wm = *reinterpret_cast<const float4*>(Wmu + k * LAT + j0);
    float4 wv = *reinterpret_cast<const float4*>(Wlv + k * LAT + j0);
    float hv = hs[n][k];
    am[0] += hv * wm.x; am[1] += hv * wm.y; am[2] += hv * wm.z; am[3] += hv * wm.w;
    al[0] += hv * wv.x; al[1] += hv * wv.y; al[2] += hv * wv.z; al[3] += hv * wv.w;
  }
  int v = nbase + n;
  if (v < NN) {
    float4 bm = *reinterpret_cast<const float4*>(bmu + j0);
    float4 bl = *reinterpret_cast<const float4*>(blv + j0);
    float4 e4 = *reinterpret_cast<const float4*>(eps + (size_t)v * LAT + j0);
    float4 mu, lv, zz;
    mu.x = am[0] + bm.x; mu.y = am[1] + bm.y; mu.z = am[2] + bm.z; mu.w = am[3] + bm.w;
    lv.x = al[0] + bl.x; lv.y = al[1] + bl.y; lv.z = al[2] + bl.z; lv.w = al[3] + bl.w;
    zz.x = mu.x + e4.x * expf(0.5f * lv.x);
    zz.y = mu.y + e4.y * expf(0.5f * lv.y);
    zz.z = mu.z + e4.z * expf(0.5f * lv.z);
    zz.w = mu.w + e4.w * expf(0.5f * lv.w);
    *reinterpret_cast<float4*>(mu_out + (size_t)v * LAT + j0) = mu;
    *reinterpret_cast<float4*>(lv_out + (size_t)v * LAT + j0) = lv;
    *reinterpret_cast<float4*>(z + (size_t)v * LAT + j0) = zz;
  }
}

// ---------------- edge decode: sigmoid(z[src] . z[dst]) ----------------
__global__ void k_decode(const int* __restrict__ src, const int* __restrict__ dst,
                         const float* __restrict__ z, float* __restrict__ probs) {
  int t = blockIdx.x * 256 + threadIdx.x;
  int e = t >> 3, part = t & 7;
  if (e >= NE) return;
  int s = src[e], d = dst[e];
  float4 a = *reinterpret_cast<const float4*>(z + (size_t)s * LAT + part * 4);
  float4 b = *reinterpret_cast<const float4*>(z + (size_t)d * LAT + part * 4);
  float p = a.x * b.x + a.y * b.y + a.z * b.z + a.w * b.w;
  p += __shfl_xor(p, 1);
  p += __shfl_xor(p, 2);
  p += __shfl_xor(p, 4);
  if (part == 0) probs[e] = 1.0f / (1.0f + expf(-p));
}

extern "C" void kernel_launch(void* const* d_in, const int* in_sizes, int n_in,
                              void* d_out, int out_size, void* d_ws, size_t ws_size,
                              hipStream_t stream) {
  const float* x   = (const float*)d_in[0];
  const int*   ei  = (const int*)d_in[1];
  const float* eps = (const float*)d_in[2];
  const float* Wl0 = (const float*)d_in[3];
  const float* Wr0 = (const float*)d_in[4];
  const float* b0  = (const float*)d_in[5];
  const float* Wl1 = (const float*)d_in[6];
  const float* Wr1 = (const float*)d_in[7];
  const float* b1  = (const float*)d_in[8];
  const float* Wmu = (const float*)d_in[9];
  const float* bmu = (const float*)d_in[10];
  const float* Wlv = (const float*)d_in[11];
  const float* blv = (const float*)d_in[12];
  const int* src = ei;
  const int* dst = ei + NE;

  // workspace layout (ints then floats), total ~56 MiB
  int* iws = (int*)d_ws;
  int* deg       = iws;                 // NN
  int* row_start = deg + NN;            // NN
  int* cursor    = row_start + NN;      // NN
  int* bsum      = cursor + NN;         // 256
  int* boff      = bsum + 256;          // 256
  int* eid       = boff + 256;          // NE
  float* h1 = (float*)(eid + NE);       // NN*CH  (z aliases this after layer 2)
  float* h2 = h1 + (size_t)NN * CH;     // NN*CH
  float* z  = h1;                       // h1 dead once h2 is computed

  float* probs  = (float*)d_out;        // NE
  float* mu_out = probs + NE;           // NN*LAT
  float* lv_out = mu_out + NN * LAT;    // NN*LAT

  hipMemsetAsync(deg, 0, NN * sizeof(int), stream);

  k_hist <<<(NE + 255) / 256, 256, 0, stream>>>(dst, deg);
  k_scan1<<<NB, 256, 0, stream>>>(deg, bsum);
  k_scan2<<<1, 256, 0, stream>>>(bsum, boff);
  k_scan3<<<NB, 256, 0, stream>>>(deg, boff, row_start, cursor);
  k_fill <<<(NE + 255) / 256, 256, 0, stream>>>(src, dst, cursor, eid);

  k_sage2<<<(NN + 31) / 32, 256, 0, stream>>>(x,  deg, row_start, eid,
                                              Wl0, Wr0, b0, h1);
  k_sage2<<<(NN + 31) / 32, 256, 0, stream>>>(h1, deg, row_start, eid,
                                              Wl1, Wr1, b1, h2);

  k_heads<<<(NN + 31) / 32, 256, 0, stream>>>(h2, eps, Wmu, bmu, Wlv, blv,
                                              mu_out, lv_out, z);
  k_decode<<<(NE * 8 + 255) / 256, 256, 0, stream>>>(src, dst, z, probs);
}

// Round 4
// 664.277 us; speedup vs baseline: 8.7025x; 1.1041x over previous
//
#include <hip/hip_runtime.h>
#include <math.h>

#define NN 50000
#define NE 1600000
#define CH 128
#define LAT 32
#define NB 196  // ceil(NN/256)

__device__ __forceinline__ unsigned short f2bf(float f) {  // RNE round to bf16
  unsigned int u = __float_as_uint(f);
  unsigned int r = u + 0x7FFFu + ((u >> 16) & 1u);
  return (unsigned short)(r >> 16);
}
__device__ __forceinline__ float bf2f(unsigned short s) {
  return __uint_as_float(((unsigned int)s) << 16);
}

// ---------------- fp32 -> bf16 table convert ----------------
__global__ void k_tobf16(const float* __restrict__ in, unsigned short* __restrict__ out,
                         int n4) {
  int i = blockIdx.x * 256 + threadIdx.x;
  if (i < n4) {
    float4 v = reinterpret_cast<const float4*>(in)[i];
    ushort4 o;
    o.x = f2bf(v.x); o.y = f2bf(v.y); o.z = f2bf(v.z); o.w = f2bf(v.w);
    reinterpret_cast<ushort4*>(out)[i] = o;
  }
}

// ---------------- CSR build ----------------
__global__ void k_hist(const int* __restrict__ dst, int* __restrict__ deg) {
  int e = blockIdx.x * 256 + threadIdx.x;
  if (e < NE) atomicAdd(&deg[dst[e]], 1);
}

__global__ void k_scan1(const int* __restrict__ deg, int* __restrict__ bsum) {
  __shared__ int red[256];
  int i = blockIdx.x * 256 + threadIdx.x;
  red[threadIdx.x] = (i < NN) ? deg[i] : 0;
  __syncthreads();
  for (int s = 128; s > 0; s >>= 1) {
    if (threadIdx.x < s) red[threadIdx.x] += red[threadIdx.x + s];
    __syncthreads();
  }
  if (threadIdx.x == 0) bsum[blockIdx.x] = red[0];
}

__global__ void k_scan2(const int* __restrict__ bsum, int* __restrict__ boff) {
  __shared__ int tmp[256];
  int t = threadIdx.x;
  int v = (t < NB) ? bsum[t] : 0;
  tmp[t] = v;
  __syncthreads();
  for (int off = 1; off < 256; off <<= 1) {
    int add = (t >= off) ? tmp[t - off] : 0;
    __syncthreads();
    tmp[t] += add;
    __syncthreads();
  }
  if (t < NB) boff[t] = tmp[t] - v;  // exclusive
}

__global__ void k_scan3(const int* __restrict__ deg, const int* __restrict__ boff,
                        int* __restrict__ row_start, int* __restrict__ cursor) {
  __shared__ int tmp[256];
  int t = threadIdx.x;
  int i = blockIdx.x * 256 + t;
  int v = (i < NN) ? deg[i] : 0;
  tmp[t] = v;
  __syncthreads();
  for (int off = 1; off < 256; off <<= 1) {
    int add = (t >= off) ? tmp[t - off] : 0;
    __syncthreads();
    tmp[t] += add;
    __syncthreads();
  }
  int excl = tmp[t] - v + boff[blockIdx.x];
  if (i < NN) { row_start[i] = excl; cursor[i] = excl; }
}

__global__ void k_fill(const int* __restrict__ src, const int* __restrict__ dst,
                       int* __restrict__ cursor, int* __restrict__ eid) {
  int e = blockIdx.x * 256 + threadIdx.x;
  if (e < NE) {
    int d = dst[e];
    int pos = atomicAdd(&cursor[d], 1);
    eid[pos] = src[e];
  }
}

// ---------------- fused SAGE layer: bf16 pull-aggregate + fp32 GEMM + ReLU ----
// out = relu( mean_{s in N(v)} featb[s] @ Wl + self[v] @ Wr + b )
// featb: bf16 gather table. feat32: optional exact fp32 self-features (layer 0).
// outf (fp32) and outb (bf16) each optional.
__global__ __launch_bounds__(256) void k_sage2(
    const unsigned short* __restrict__ featb, const float* __restrict__ feat32,
    const int* __restrict__ deg, const int* __restrict__ row_start,
    const int* __restrict__ eid,
    const float* __restrict__ Wl, const float* __restrict__ Wr,
    const float* __restrict__ bias,
    float* __restrict__ outf, unsigned short* __restrict__ outb) {
  __shared__ float mean_s[32][128];
  __shared__ float h_s[32][128];
  int tid = threadIdx.x;
  int nbase = blockIdx.x * 32;
  int hw = tid >> 5, q = tid & 31;

  // Phase 1: pull aggregation (32 lanes x ushort4 = 256B coalesced row read)
  for (int n = hw; n < 32; n += 8) {
    int v = nbase + n;
    float ax = 0.f, ay = 0.f, az = 0.f, aw = 0.f;
    float4 hh = make_float4(0.f, 0.f, 0.f, 0.f);
    if (v < NN) {
      int r0 = row_start[v];
      int dg = deg[v];
      int i = 0;
      for (; i + 3 < dg; i += 4) {
        int s0 = eid[r0 + i + 0];
        int s1 = eid[r0 + i + 1];
        int s2 = eid[r0 + i + 2];
        int s3 = eid[r0 + i + 3];
        ushort4 a = *reinterpret_cast<const ushort4*>(featb + (size_t)s0 * CH + q * 4);
        ushort4 b = *reinterpret_cast<const ushort4*>(featb + (size_t)s1 * CH + q * 4);
        ushort4 c = *reinterpret_cast<const ushort4*>(featb + (size_t)s2 * CH + q * 4);
        ushort4 d = *reinterpret_cast<const ushort4*>(featb + (size_t)s3 * CH + q * 4);
        ax += bf2f(a.x) + bf2f(b.x) + bf2f(c.x) + bf2f(d.x);
        ay += bf2f(a.y) + bf2f(b.y) + bf2f(c.y) + bf2f(d.y);
        az += bf2f(a.z) + bf2f(b.z) + bf2f(c.z) + bf2f(d.z);
        aw += bf2f(a.w) + bf2f(b.w) + bf2f(c.w) + bf2f(d.w);
      }
      for (; i < dg; ++i) {
        int s0 = eid[r0 + i];
        ushort4 a = *reinterpret_cast<const ushort4*>(featb + (size_t)s0 * CH + q * 4);
        ax += bf2f(a.x); ay += bf2f(a.y); az += bf2f(a.z); aw += bf2f(a.w);
      }
      float r = 1.0f / (float)max(dg, 1);
      ax *= r; ay *= r; az *= r; aw *= r;
      if (feat32) {
        hh = *reinterpret_cast<const float4*>(feat32 + (size_t)v * CH + q * 4);
      } else {
        ushort4 hb = *reinterpret_cast<const ushort4*>(featb + (size_t)v * CH + q * 4);
        hh = make_float4(bf2f(hb.x), bf2f(hb.y), bf2f(hb.z), bf2f(hb.w));
      }
    }
    *reinterpret_cast<float4*>(&mean_s[n][q * 4]) = make_float4(ax, ay, az, aw);
    *reinterpret_cast<float4*>(&h_s[n][q * 4]) = hh;
  }
  __syncthreads();

  // Phase 2: GEMM  out[32][128] = mean @ Wl + h @ Wr + b, ReLU
  int jg = tid & 31, ng = tid >> 5;
  int j0 = jg * 4, nl = ng * 4;
  float acc[4][4];
#pragma unroll
  for (int a = 0; a < 4; a++)
#pragma unroll
    for (int b = 0; b < 4; b++) acc[a][b] = 0.f;

#pragma unroll 4
  for (int k = 0; k < 128; ++k) {
    float4 wl = *reinterpret_cast<const float4*>(Wl + k * CH + j0);
    float4 wr = *reinterpret_cast<const float4*>(Wr + k * CH + j0);
#pragma unroll
    for (int n = 0; n < 4; ++n) {
      float m = mean_s[nl + n][k];
      float hv = h_s[nl + n][k];
      acc[n][0] += m * wl.x + hv * wr.x;
      acc[n][1] += m * wl.y + hv * wr.y;
      acc[n][2] += m * wl.z + hv * wr.z;
      acc[n][3] += m * wl.w + hv * wr.w;
    }
  }

  float4 bb = *reinterpret_cast<const float4*>(bias + j0);
#pragma unroll
  for (int n = 0; n < 4; ++n) {
    int v = nbase + nl + n;
    if (v < NN) {
      float4 o;
      o.x = fmaxf(acc[n][0] + bb.x, 0.f);
      o.y = fmaxf(acc[n][1] + bb.y, 0.f);
      o.z = fmaxf(acc[n][2] + bb.z, 0.f);
      o.w = fmaxf(acc[n][3] + bb.w, 0.f);
      if (outf) *reinterpret_cast<float4*>(outf + (size_t)v * CH + j0) = o;
      if (outb) {
        ushort4 ob;
        ob.x = f2bf(o.x); ob.y = f2bf(o.y); ob.z = f2bf(o.z); ob.w = f2bf(o.w);
        *reinterpret_cast<ushort4*>(outb + (size_t)v * CH + j0) = ob;
      }
    }
  }
}

// ---------------- mu / logvar heads + reparameterize ----------------
__global__ __launch_bounds__(256) void k_heads(
    const float* __restrict__ h2, const float* __restrict__ eps,
    const float* __restrict__ Wmu, const float* __restrict__ bmu,
    const float* __restrict__ Wlv, const float* __restrict__ blv,
    float* __restrict__ mu_out, float* __restrict__ lv_out,
    float* __restrict__ z) {
  __shared__ float hs[32][132];  // +4 pad kills bank conflict on hs[n][k]
  int tid = threadIdx.x;
  int nbase = blockIdx.x * 32;

  for (int f = tid; f < 1024; f += 256) {
    int row = f >> 5;
    int c4 = (f & 31) * 4;
    int v = nbase + row;
    float4 hh = make_float4(0.f, 0.f, 0.f, 0.f);
    if (v < NN) hh = *reinterpret_cast<const float4*>(h2 + (size_t)v * CH + c4);
    *reinterpret_cast<float4*>(&hs[row][c4]) = hh;
  }
  __syncthreads();

  int n = tid >> 3;
  int j0 = (tid & 7) * 4;
  float am[4] = {0.f, 0.f, 0.f, 0.f};
  float al[4] = {0.f, 0.f, 0.f, 0.f};
#pragma unroll 4
  for (int k = 0; k < 128; ++k) {
    float4 wm = *reinterpret_cast<const float4*>(Wmu + k * LAT + j0);
    float4 wv = *reinterpret_cast<const float4*>(Wlv + k * LAT + j0);
    float hv = hs[n][k];
    am[0] += hv * wm.x; am[1] += hv * wm.y; am[2] += hv * wm.z; am[3] += hv * wm.w;
    al[0] += hv * wv.x; al[1] += hv * wv.y; al[2] += hv * wv.z; al[3] += hv * wv.w;
  }
  int v = nbase + n;
  if (v < NN) {
    float4 bm = *reinterpret_cast<const float4*>(bmu + j0);
    float4 bl = *reinterpret_cast<const float4*>(blv + j0);
    float4 e4 = *reinterpret_cast<const float4*>(eps + (size_t)v * LAT + j0);
    float4 mu, lv, zz;
    mu.x = am[0] + bm.x; mu.y = am[1] + bm.y; mu.z = am[2] + bm.z; mu.w = am[3] + bm.w;
    lv.x = al[0] + bl.x; lv.y = al[1] + bl.y; lv.z = al[2] + bl.z; lv.w = al[3] + bl.w;
    zz.x = mu.x + e4.x * expf(0.5f * lv.x);
    zz.y = mu.y + e4.y * expf(0.5f * lv.y);
    zz.z = mu.z + e4.z * expf(0.5f * lv.z);
    zz.w = mu.w + e4.w * expf(0.5f * lv.w);
    *reinterpret_cast<float4*>(mu_out + (size_t)v * LAT + j0) = mu;
    *reinterpret_cast<float4*>(lv_out + (size_t)v * LAT + j0) = lv;
    *reinterpret_cast<float4*>(z + (size_t)v * LAT + j0) = zz;
  }
}

// ---------------- edge decode: sigmoid(z[src] . z[dst]) ----------------
__global__ void k_decode(const int* __restrict__ src, const int* __restrict__ dst,
                         const float* __restrict__ z, float* __restrict__ probs) {
  int t = blockIdx.x * 256 + threadIdx.x;
  int e = t >> 3, part = t & 7;
  if (e >= NE) return;
  int s = src[e], d = dst[e];
  float4 a = *reinterpret_cast<const float4*>(z + (size_t)s * LAT + part * 4);
  float4 b = *reinterpret_cast<const float4*>(z + (size_t)d * LAT + part * 4);
  float p = a.x * b.x + a.y * b.y + a.z * b.z + a.w * b.w;
  p += __shfl_xor(p, 1);
  p += __shfl_xor(p, 2);
  p += __shfl_xor(p, 4);
  if (part == 0) probs[e] = 1.0f / (1.0f + expf(-p));
}

extern "C" void kernel_launch(void* const* d_in, const int* in_sizes, int n_in,
                              void* d_out, int out_size, void* d_ws, size_t ws_size,
                              hipStream_t stream) {
  const float* x   = (const float*)d_in[0];
  const int*   ei  = (const int*)d_in[1];
  const float* eps = (const float*)d_in[2];
  const float* Wl0 = (const float*)d_in[3];
  const float* Wr0 = (const float*)d_in[4];
  const float* b0  = (const float*)d_in[5];
  const float* Wl1 = (const float*)d_in[6];
  const float* Wr1 = (const float*)d_in[7];
  const float* b1  = (const float*)d_in[8];
  const float* Wmu = (const float*)d_in[9];
  const float* bmu = (const float*)d_in[10];
  const float* Wlv = (const float*)d_in[11];
  const float* blv = (const float*)d_in[12];
  const int* src = ei;
  const int* dst = ei + NE;

  // workspace layout, ~58 MiB total
  int* iws = (int*)d_ws;
  int* deg       = iws;                       // NN
  int* row_start = deg + NN;                  // NN
  int* cursor    = row_start + NN;            // NN
  int* bsum      = cursor + NN;               // 256
  int* boff      = bsum + 256;                // 256
  int* eid       = boff + 256;                // NE
  unsigned short* xb  = (unsigned short*)(eid + NE);      // NN*CH bf16 (12.8MB)
  unsigned short* h1b = xb + (size_t)NN * CH;             // NN*CH bf16 (12.8MB)
  float* h2 = (float*)(h1b + (size_t)NN * CH);            // NN*CH fp32 (25.6MB)
  float* z  = (float*)h1b;  // h1b dead after layer-2 k_sage2; 16B-aligned

  float* probs  = (float*)d_out;              // NE
  float* mu_out = probs + NE;                 // NN*LAT
  float* lv_out = mu_out + NN * LAT;          // NN*LAT

  hipMemsetAsync(deg, 0, NN * sizeof(int), stream);

  k_tobf16<<<(NN * CH / 4 + 255) / 256, 256, 0, stream>>>(x, xb, NN * CH / 4);
  k_hist <<<(NE + 255) / 256, 256, 0, stream>>>(dst, deg);
  k_scan1<<<NB, 256, 0, stream>>>(deg, bsum);
  k_scan2<<<1, 256, 0, stream>>>(bsum, boff);
  k_scan3<<<NB, 256, 0, stream>>>(deg, boff, row_start, cursor);
  k_fill <<<(NE + 255) / 256, 256, 0, stream>>>(src, dst, cursor, eid);

  // layer 0: gather bf16(x), self exact fp32 x, emit bf16 h1 only
  k_sage2<<<(NN + 31) / 32, 256, 0, stream>>>(xb, x, deg, row_start, eid,
                                              Wl0, Wr0, b0, nullptr, h1b);
  // layer 1: gather + self bf16 h1, emit fp32 h2
  k_sage2<<<(NN + 31) / 32, 256, 0, stream>>>(h1b, nullptr, deg, row_start, eid,
                                              Wl1, Wr1, b1, h2, nullptr);

  k_heads<<<(NN + 31) / 32, 256, 0, stream>>>(h2, eps, Wmu, bmu, Wlv, blv,
                                              mu_out, lv_out, z);
  k_decode<<<(NE * 8 + 255) / 256, 256, 0, stream>>>(src, dst, z, probs);
}

// Round 5
// 659.460 us; speedup vs baseline: 8.7660x; 1.0073x over previous
//
#include <hip/hip_runtime.h>
#include <math.h>

#define NN 50000
#define NE 1600000
#define CH 128
#define LAT 32
#define NB 196  // ceil(NN/256)

__device__ __forceinline__ unsigned short f2bf(float f) {  // RNE round to bf16
  unsigned int u = __float_as_uint(f);
  unsigned int r = u + 0x7FFFu + ((u >> 16) & 1u);
  return (unsigned short)(r >> 16);
}
__device__ __forceinline__ float bf2f(unsigned short s) {
  return __uint_as_float(((unsigned int)s) << 16);
}
__device__ __forceinline__ float bflo(unsigned int u) {  // low bf16 of packed pair
  return __uint_as_float(u << 16);
}
__device__ __forceinline__ float bfhi(unsigned int u) {  // high bf16 of packed pair
  return __uint_as_float(u & 0xffff0000u);
}

// ---------------- fp32 -> bf16 table convert ----------------
__global__ void k_tobf16(const float* __restrict__ in, unsigned short* __restrict__ out,
                         int n4) {
  int i = blockIdx.x * 256 + threadIdx.x;
  if (i < n4) {
    float4 v = reinterpret_cast<const float4*>(in)[i];
    ushort4 o;
    o.x = f2bf(v.x); o.y = f2bf(v.y); o.z = f2bf(v.z); o.w = f2bf(v.w);
    reinterpret_cast<ushort4*>(out)[i] = o;
  }
}

// ---------------- CSR build ----------------
__global__ void k_hist(const int* __restrict__ dst, int* __restrict__ deg) {
  int e = blockIdx.x * 256 + threadIdx.x;
  if (e < NE) atomicAdd(&deg[dst[e]], 1);
}

__global__ void k_scan1(const int* __restrict__ deg, int* __restrict__ bsum) {
  __shared__ int red[256];
  int i = blockIdx.x * 256 + threadIdx.x;
  red[threadIdx.x] = (i < NN) ? deg[i] : 0;
  __syncthreads();
  for (int s = 128; s > 0; s >>= 1) {
    if (threadIdx.x < s) red[threadIdx.x] += red[threadIdx.x + s];
    __syncthreads();
  }
  if (threadIdx.x == 0) bsum[blockIdx.x] = red[0];
}

__global__ void k_scan2(const int* __restrict__ bsum, int* __restrict__ boff) {
  __shared__ int tmp[256];
  int t = threadIdx.x;
  int v = (t < NB) ? bsum[t] : 0;
  tmp[t] = v;
  __syncthreads();
  for (int off = 1; off < 256; off <<= 1) {
    int add = (t >= off) ? tmp[t - off] : 0;
    __syncthreads();
    tmp[t] += add;
    __syncthreads();
  }
  if (t < NB) boff[t] = tmp[t] - v;  // exclusive
}

__global__ void k_scan3(const int* __restrict__ deg, const int* __restrict__ boff,
                        int* __restrict__ row_start, int* __restrict__ cursor) {
  __shared__ int tmp[256];
  int t = threadIdx.x;
  int i = blockIdx.x * 256 + t;
  int v = (i < NN) ? deg[i] : 0;
  tmp[t] = v;
  __syncthreads();
  for (int off = 1; off < 256; off <<= 1) {
    int add = (t >= off) ? tmp[t - off] : 0;
    __syncthreads();
    tmp[t] += add;
    __syncthreads();
  }
  int excl = tmp[t] - v + boff[blockIdx.x];
  if (i < NN) { row_start[i] = excl; cursor[i] = excl; }
}

__global__ void k_fill(const int* __restrict__ src, const int* __restrict__ dst,
                       int* __restrict__ cursor, int* __restrict__ eid) {
  int e = blockIdx.x * 256 + threadIdx.x;
  if (e < NE) {
    int d = dst[e];
    int pos = atomicAdd(&cursor[d], 1);
    eid[pos] = src[e];
  }
}

// ---------------- fused SAGE layer: bf16 pull-aggregate + fp32 GEMM + ReLU ----
// outb[v] = bf16( relu( mean_{s in N(v)} featb[s] @ Wl + self[v] @ Wr + b ) )
// LDS tiles transposed ([ch][node], bf16, pad 36) so phase 2 reads all 4 nodes
// of a channel with one ds_read_b64. 18 KB LDS -> 8 blocks/CU (wave-capped).
__global__ __launch_bounds__(256, 8) void k_sage2(
    const unsigned short* __restrict__ featb, const float* __restrict__ feat32,
    const int* __restrict__ deg, const int* __restrict__ row_start,
    const int* __restrict__ eid,
    const float* __restrict__ Wl, const float* __restrict__ Wr,
    const float* __restrict__ bias, unsigned short* __restrict__ outb) {
  __shared__ __align__(16) unsigned short mean_t[128][36];
  __shared__ __align__(16) unsigned short h_t[128][36];
  int tid = threadIdx.x;
  int nbase = blockIdx.x * 32;
  int hw = tid >> 5, q = tid & 31;
  int q4 = q * 4;

  // Phase 1: pull aggregation (32 lanes x ushort4 = 256B coalesced row read)
  for (int n = hw; n < 32; n += 8) {
    int v = nbase + n;
    float ax = 0.f, ay = 0.f, az = 0.f, aw = 0.f;
    float hx = 0.f, hy = 0.f, hz = 0.f, hwv = 0.f;
    if (v < NN) {
      int r0 = row_start[v];
      int dg = deg[v];
      int i = 0;
      for (; i + 3 < dg; i += 4) {
        int s0 = eid[r0 + i + 0];
        int s1 = eid[r0 + i + 1];
        int s2 = eid[r0 + i + 2];
        int s3 = eid[r0 + i + 3];
        ushort4 a = *reinterpret_cast<const ushort4*>(featb + (size_t)s0 * CH + q4);
        ushort4 b = *reinterpret_cast<const ushort4*>(featb + (size_t)s1 * CH + q4);
        ushort4 c = *reinterpret_cast<const ushort4*>(featb + (size_t)s2 * CH + q4);
        ushort4 d = *reinterpret_cast<const ushort4*>(featb + (size_t)s3 * CH + q4);
        ax += bf2f(a.x) + bf2f(b.x) + bf2f(c.x) + bf2f(d.x);
        ay += bf2f(a.y) + bf2f(b.y) + bf2f(c.y) + bf2f(d.y);
        az += bf2f(a.z) + bf2f(b.z) + bf2f(c.z) + bf2f(d.z);
        aw += bf2f(a.w) + bf2f(b.w) + bf2f(c.w) + bf2f(d.w);
      }
      for (; i < dg; ++i) {
        int s0 = eid[r0 + i];
        ushort4 a = *reinterpret_cast<const ushort4*>(featb + (size_t)s0 * CH + q4);
        ax += bf2f(a.x); ay += bf2f(a.y); az += bf2f(a.z); aw += bf2f(a.w);
      }
      float r = 1.0f / (float)max(dg, 1);
      ax *= r; ay *= r; az *= r; aw *= r;
      if (feat32) {
        float4 hh = *reinterpret_cast<const float4*>(feat32 + (size_t)v * CH + q4);
        hx = hh.x; hy = hh.y; hz = hh.z; hwv = hh.w;
      } else {
        ushort4 hb = *reinterpret_cast<const ushort4*>(featb + (size_t)v * CH + q4);
        hx = bf2f(hb.x); hy = bf2f(hb.y); hz = bf2f(hb.z); hwv = bf2f(hb.w);
      }
    }
    // transposed bf16 stores: channel-major
    mean_t[q4 + 0][n] = f2bf(ax);
    mean_t[q4 + 1][n] = f2bf(ay);
    mean_t[q4 + 2][n] = f2bf(az);
    mean_t[q4 + 3][n] = f2bf(aw);
    h_t[q4 + 0][n] = f2bf(hx);
    h_t[q4 + 1][n] = f2bf(hy);
    h_t[q4 + 2][n] = f2bf(hz);
    h_t[q4 + 3][n] = f2bf(hwv);
  }
  __syncthreads();

  // Phase 2: out[32][128] = mean @ Wl + h @ Wr + b, ReLU  (fp32 accum)
  int jg = tid & 31, ng = tid >> 5;
  int j0 = jg * 4, nl = ng * 4;
  float acc[4][4];
#pragma unroll
  for (int a = 0; a < 4; a++)
#pragma unroll
    for (int b = 0; b < 4; b++) acc[a][b] = 0.f;

#pragma unroll 2
  for (int k = 0; k < 128; ++k) {
    float4 wl = *reinterpret_cast<const float4*>(Wl + k * CH + j0);
    float4 wr = *reinterpret_cast<const float4*>(Wr + k * CH + j0);
    uint2 mp = *reinterpret_cast<const uint2*>(&mean_t[k][nl]);
    uint2 hp = *reinterpret_cast<const uint2*>(&h_t[k][nl]);
    float mn[4] = {bflo(mp.x), bfhi(mp.x), bflo(mp.y), bfhi(mp.y)};
    float hn[4] = {bflo(hp.x), bfhi(hp.x), bflo(hp.y), bfhi(hp.y)};
#pragma unroll
    for (int n = 0; n < 4; ++n) {
      acc[n][0] += mn[n] * wl.x + hn[n] * wr.x;
      acc[n][1] += mn[n] * wl.y + hn[n] * wr.y;
      acc[n][2] += mn[n] * wl.z + hn[n] * wr.z;
      acc[n][3] += mn[n] * wl.w + hn[n] * wr.w;
    }
  }

  float4 bb = *reinterpret_cast<const float4*>(bias + j0);
#pragma unroll
  for (int n = 0; n < 4; ++n) {
    int v = nbase + nl + n;
    if (v < NN) {
      ushort4 ob;
      ob.x = f2bf(fmaxf(acc[n][0] + bb.x, 0.f));
      ob.y = f2bf(fmaxf(acc[n][1] + bb.y, 0.f));
      ob.z = f2bf(fmaxf(acc[n][2] + bb.z, 0.f));
      ob.w = f2bf(fmaxf(acc[n][3] + bb.w, 0.f));
      *reinterpret_cast<ushort4*>(outb + (size_t)v * CH + j0) = ob;
    }
  }
}

// ---------------- mu / logvar heads + reparameterize (bf16 h2 in, bf16 z out) --
__global__ __launch_bounds__(256) void k_heads(
    const unsigned short* __restrict__ h2b, const float* __restrict__ eps,
    const float* __restrict__ Wmu, const float* __restrict__ bmu,
    const float* __restrict__ Wlv, const float* __restrict__ blv,
    float* __restrict__ mu_out, float* __restrict__ lv_out,
    unsigned short* __restrict__ zb) {
  __shared__ float hs[32][132];  // +4 pad kills bank conflict on hs[n][k]
  int tid = threadIdx.x;
  int nbase = blockIdx.x * 32;

  for (int f = tid; f < 1024; f += 256) {
    int row = f >> 5;
    int c4 = (f & 31) * 4;
    int v = nbase + row;
    float4 hh = make_float4(0.f, 0.f, 0.f, 0.f);
    if (v < NN) {
      ushort4 hb = *reinterpret_cast<const ushort4*>(h2b + (size_t)v * CH + c4);
      hh = make_float4(bf2f(hb.x), bf2f(hb.y), bf2f(hb.z), bf2f(hb.w));
    }
    *reinterpret_cast<float4*>(&hs[row][c4]) = hh;
  }
  __syncthreads();

  int n = tid >> 3;
  int j0 = (tid & 7) * 4;
  float am[4] = {0.f, 0.f, 0.f, 0.f};
  float al[4] = {0.f, 0.f, 0.f, 0.f};
#pragma unroll 4
  for (int k = 0; k < 128; ++k) {
    float4 wm = *reinterpret_cast<const float4*>(Wmu + k * LAT + j0);
    float4 wv = *reinterpret_cast<const float4*>(Wlv + k * LAT + j0);
    float hv = hs[n][k];
    am[0] += hv * wm.x; am[1] += hv * wm.y; am[2] += hv * wm.z; am[3] += hv * wm.w;
    al[0] += hv * wv.x; al[1] += hv * wv.y; al[2] += hv * wv.z; al[3] += hv * wv.w;
  }
  int v = nbase + n;
  if (v < NN) {
    float4 bm = *reinterpret_cast<const float4*>(bmu + j0);
    float4 bl = *reinterpret_cast<const float4*>(blv + j0);
    float4 e4 = *reinterpret_cast<const float4*>(eps + (size_t)v * LAT + j0);
    float4 mu, lv;
    mu.x = am[0] + bm.x; mu.y = am[1] + bm.y; mu.z = am[2] + bm.z; mu.w = am[3] + bm.w;
    lv.x = al[0] + bl.x; lv.y = al[1] + bl.y; lv.z = al[2] + bl.z; lv.w = al[3] + bl.w;
    ushort4 zz;
    zz.x = f2bf(mu.x + e4.x * expf(0.5f * lv.x));
    zz.y = f2bf(mu.y + e4.y * expf(0.5f * lv.y));
    zz.z = f2bf(mu.z + e4.z * expf(0.5f * lv.z));
    zz.w = f2bf(mu.w + e4.w * expf(0.5f * lv.w));
    *reinterpret_cast<float4*>(mu_out + (size_t)v * LAT + j0) = mu;
    *reinterpret_cast<float4*>(lv_out + (size_t)v * LAT + j0) = lv;
    *reinterpret_cast<ushort4*>(zb + (size_t)v * LAT + j0) = zz;
  }
}

// ---------------- edge decode: sigmoid(z[src] . z[dst]), bf16 z ----------------
__global__ void k_decode(const int* __restrict__ src, const int* __restrict__ dst,
                         const unsigned short* __restrict__ zb,
                         float* __restrict__ probs) {
  int t = blockIdx.x * 256 + threadIdx.x;
  int e = t >> 3, part = t & 7;
  if (e >= NE) return;
  int s = src[e], d = dst[e];
  ushort4 a = *reinterpret_cast<const ushort4*>(zb + (size_t)s * LAT + part * 4);
  ushort4 b = *reinterpret_cast<const ushort4*>(zb + (size_t)d * LAT + part * 4);
  float p = bf2f(a.x) * bf2f(b.x) + bf2f(a.y) * bf2f(b.y) +
            bf2f(a.z) * bf2f(b.z) + bf2f(a.w) * bf2f(b.w);
  p += __shfl_xor(p, 1);
  p += __shfl_xor(p, 2);
  p += __shfl_xor(p, 4);
  if (part == 0) probs[e] = 1.0f / (1.0f + expf(-p));
}

extern "C" void kernel_launch(void* const* d_in, const int* in_sizes, int n_in,
                              void* d_out, int out_size, void* d_ws, size_t ws_size,
                              hipStream_t stream) {
  const float* x   = (const float*)d_in[0];
  const int*   ei  = (const int*)d_in[1];
  const float* eps = (const float*)d_in[2];
  const float* Wl0 = (const float*)d_in[3];
  const float* Wr0 = (const float*)d_in[4];
  const float* b0  = (const float*)d_in[5];
  const float* Wl1 = (const float*)d_in[6];
  const float* Wr1 = (const float*)d_in[7];
  const float* b1  = (const float*)d_in[8];
  const float* Wmu = (const float*)d_in[9];
  const float* bmu = (const float*)d_in[10];
  const float* Wlv = (const float*)d_in[11];
  const float* blv = (const float*)d_in[12];
  const int* src = ei;
  const int* dst = ei + NE;

  // workspace layout (~45.5 MiB)
  int* iws = (int*)d_ws;
  int* deg       = iws;                       // NN
  int* row_start = deg + NN;                  // NN
  int* cursor    = row_start + NN;            // NN
  int* bsum      = cursor + NN;               // 256
  int* boff      = bsum + 256;                // 256
  int* eid       = boff + 256;                // NE
  unsigned short* xb  = (unsigned short*)(eid + NE);  // NN*CH bf16
  unsigned short* h1b = xb + (size_t)NN * CH;         // NN*CH bf16
  unsigned short* h2b = h1b + (size_t)NN * CH;        // NN*CH bf16
  unsigned short* zb  = xb;  // xb dead after layer 0; NN*LAT bf16 fits

  float* probs  = (float*)d_out;              // NE
  float* mu_out = probs + NE;                 // NN*LAT
  float* lv_out = mu_out + NN * LAT;          // NN*LAT

  hipMemsetAsync(deg, 0, NN * sizeof(int), stream);

  k_tobf16<<<(NN * CH / 4 + 255) / 256, 256, 0, stream>>>(x, xb, NN * CH / 4);
  k_hist <<<(NE + 255) / 256, 256, 0, stream>>>(dst, deg);
  k_scan1<<<NB, 256, 0, stream>>>(deg, bsum);
  k_scan2<<<1, 256, 0, stream>>>(bsum, boff);
  k_scan3<<<NB, 256, 0, stream>>>(deg, boff, row_start, cursor);
  k_fill <<<(NE + 255) / 256, 256, 0, stream>>>(src, dst, cursor, eid);

  // layer 0: gather bf16(x), self exact fp32 x, emit bf16 h1
  k_sage2<<<(NN + 31) / 32, 256, 0, stream>>>(xb, x, deg, row_start, eid,
                                              Wl0, Wr0, b0, h1b);
  // layer 1: gather + self bf16 h1, emit bf16 h2
  k_sage2<<<(NN + 31) / 32, 256, 0, stream>>>(h1b, nullptr, deg, row_start, eid,
                                              Wl1, Wr1, b1, h2b);

  k_heads<<<(NN + 31) / 32, 256, 0, stream>>>(h2b, eps, Wmu, bmu, Wlv, blv,
                                              mu_out, lv_out, zb);
  k_decode<<<(NE * 8 + 255) / 256, 256, 0, stream>>>(src, dst, zb, probs);
}